// Round 15
// baseline (203.094 us; speedup 1.0000x reference)
//
#include <hip/hip_runtime.h>
#include <math.h>

#define NN 100000
#define NE 800000
#define NB 512          // dst buckets for CSR fill
#define CAP 2048        // padded per-bucket capacity (mean 1562, sigma 39.5)
#define EPB 4096        // edges per bin block
#define LIMC (NB * CAP - 1)

typedef short bf16x8 __attribute__((ext_vector_type(8)));
typedef float f32x4 __attribute__((ext_vector_type(4)));
typedef unsigned short u16x8 __attribute__((ext_vector_type(8)));
typedef unsigned short u16x4 __attribute__((ext_vector_type(4)));

__device__ __forceinline__ float bf2f(unsigned short u) {
    union { unsigned u32; float f; } c; c.u32 = ((unsigned)u) << 16; return c.f;
}
__device__ __forceinline__ unsigned short f2bf(float f) {
    union { float f; unsigned u; } c; c.f = f;
    unsigned u = c.u;
    unsigned r = (u + 0x7fffu + ((u >> 16) & 1u)) >> 16;   // RNE
    return (unsigned short)r;
}
__device__ __forceinline__ int bucket_of(int d) {
    return (int)(((long long)d * NB) / NN);
}
__device__ __forceinline__ int node_start_of(int b) {
    return (int)(((long long)b * NN) / NB);
}

// ---------------- fused prep: log1p + weight pack + gcursor zero -------------
__global__ __launch_bounds__(256) void prep_kernel(
        const float* __restrict__ x, unsigned short* __restrict__ h,
        const float* __restrict__ Wself, const float* __restrict__ Wneigh,
        const float* __restrict__ fcw, const float* __restrict__ w21,
        const float* __restrict__ w22, unsigned short* __restrict__ pack,
        int* __restrict__ gcursor) {
    int i = blockIdx.x * 256 + threadIdx.x;
    if (i < NN * 16) {
        float4 v = ((const float4*)x)[i];
        u16x4 o;
        o[0] = f2bf(__logf(v.x + 1.f)); o[1] = f2bf(__logf(v.y + 1.f));
        o[2] = f2bf(__logf(v.z + 1.f)); o[3] = f2bf(__logf(v.w + 1.f));
        ((u16x4*)h)[i] = o;
    }
    if (i < 9 * 4096) {
        int m = i / 4096, r = i % 4096;
        int e = r & 7, l = (r >> 3) & 63, kb = (r >> 9) & 1, nt = r >> 10;
        int k = kb * 32 + (l >> 4) * 8 + e;
        int n = nt * 16 + (l & 15);
        const float* src;
        if (m < 3) src = Wself + m * 4096;
        else if (m < 6) src = Wneigh + (m - 3) * 4096;
        else if (m == 6) src = fcw;
        else if (m == 7) src = w21;
        else src = w22;
        pack[i] = f2bf(src[k * 64 + n]);
    }
    if (i < NB) gcursor[i] = 0;
}

// ---------------- CSR build: padded buckets ----------------

__global__ __launch_bounds__(256) void bin_edges_kernel(
        const int* __restrict__ src, const int* __restrict__ dst,
        int* __restrict__ gcursor, int* __restrict__ pairs) {
    __shared__ int hist[NB];
    __shared__ int base[NB];
    int e0 = blockIdx.x * EPB;
    int e1 = min(e0 + EPB, NE);
    for (int i = threadIdx.x; i < NB; i += 256) hist[i] = 0;
    __syncthreads();
    for (int e = e0 + threadIdx.x; e < e1; e += 256)
        atomicAdd(&hist[bucket_of(dst[e])], 1);
    __syncthreads();
    for (int i = threadIdx.x; i < NB; i += 256) {
        int c = hist[i];
        base[i] = c ? atomicAdd(&gcursor[i], c) : 0;
        hist[i] = 0;
    }
    __syncthreads();
    for (int e = e0 + threadIdx.x; e < e1; e += 256) {
        int d = dst[e];
        int b = bucket_of(d);
        int li = d - node_start_of(b);          // < 196, fits 8 bits
        int r = atomicAdd(&hist[b], 1);
        unsigned loc = (unsigned)(base[b] + r);
        if (loc < CAP) pairs[b * CAP + loc] = (src[e] << 8) | li;  // overflow -> drop
    }
}

__global__ __launch_bounds__(256) void csr_place_kernel(
        const int* __restrict__ pairs, const int* __restrict__ gcursor,
        int* __restrict__ row_ptr, int* __restrict__ row_cnt,
        int* __restrict__ col) {
    int b = blockIdx.x;
    int ns = node_start_of(b);
    int cnt = node_start_of(b + 1) - ns;     // <= 196
    int eb = b * CAP;
    int ecount = min(gcursor[b], CAP);
    __shared__ int cur[200];
    __shared__ int off[200];
    for (int i = threadIdx.x; i < cnt; i += 256) cur[i] = 0;
    __syncthreads();
    for (int p = threadIdx.x; p < ecount; p += 256) {
        int li = pairs[eb + p] & 255;
        if (li < cnt) atomicAdd(&cur[li], 1);
    }
    __syncthreads();
    if (threadIdx.x == 0) {
        int run = 0;
        for (int i = 0; i < cnt; i++) { off[i] = run; run += cur[i]; }
    }
    __syncthreads();
    for (int i = threadIdx.x; i < cnt; i += 256) {
        int c = cur[i];
        row_ptr[ns + i] = eb + off[i];
        row_cnt[ns + i] = c;
        cur[i] = 0;
    }
    __syncthreads();
    for (int p = threadIdx.x; p < ecount; p += 256) {
        int pr = pairs[eb + p];
        int li = pr & 255;
        if (li < cnt) {
            int pos = atomicAdd(&cur[li], 1);
            unsigned q = (unsigned)(off[li] + pos);
            if (q < CAP) col[eb + q] = pr >> 8;   // guard: skip, not fault
        }
    }
}

// ---------------- aggregate: one wave per 4 nodes (deep MLP) -----------------
// lane = (slot = lane>>3 in 0..7, chunk f = (lane&7)*8 bf16). 4 nodes' gathers
// are issued with independent accumulators (up to 8 x 1KB loads in flight per
// wave vs 1 before -> higher random-gather BW per Little's law). Inactive
// lanes read row 0 (cached) via cndmask so no exec-mask serialization.
__global__ __launch_bounds__(256) void aggregate_kernel(
        const unsigned short* __restrict__ h, const int* __restrict__ row_ptr,
        const int* __restrict__ row_cnt, const int* __restrict__ col,
        unsigned short* __restrict__ out) {
    int gw = (blockIdx.x * 256 + threadIdx.x) >> 6;   // global wave id
    int lane = threadIdx.x & 63;
    int slot = lane >> 3;
    int f = (lane & 7) * 8;
    int node0 = gw * 4;
    if (node0 >= NN) return;

    int beg[4], dg[4];
    #pragma unroll
    for (int i = 0; i < 4; i++) {
        int n = node0 + i;
        beg[i] = (n < NN) ? row_ptr[n] : 0;
        dg[i]  = (n < NN) ? row_cnt[n] : 0;
    }

    float acc[4][8];
    #pragma unroll
    for (int i = 0; i < 4; i++)
        #pragma unroll
        for (int j = 0; j < 8; j++) acc[i][j] = 0.f;

    // batched phase: neighbors 0..15 of all 4 nodes, loads issued back-to-back
    #pragma unroll
    for (int i = 0; i < 4; i++) {
        int p0 = beg[i] + slot;
        int p1 = p0 + 8;
        bool h0 = slot < dg[i];
        bool h1 = slot + 8 < dg[i];
        unsigned c0 = h0 ? (unsigned)col[min(p0, LIMC)] : 0u;
        unsigned c1 = h1 ? (unsigned)col[min(p1, LIMC)] : 0u;
        c0 = min(c0, (unsigned)(NN - 1));
        c1 = min(c1, (unsigned)(NN - 1));
        u16x8 v0 = *(const u16x8*)(h + (size_t)c0 * 64 + f);
        u16x8 v1 = *(const u16x8*)(h + (size_t)c1 * 64 + f);
        if (h0) {
            #pragma unroll
            for (int j = 0; j < 8; j++) acc[i][j] += bf2f(v0[j]);
        }
        if (h1) {
            #pragma unroll
            for (int j = 0; j < 8; j++) acc[i][j] += bf2f(v1[j]);
        }
    }

    // rare tail (deg > 16, ~0.3% of nodes): serial per node
    #pragma unroll
    for (int i = 0; i < 4; i++) {
        int end = beg[i] + dg[i];
        for (int p = beg[i] + 16 + slot; p < end; p += 8) {
            unsigned c = min((unsigned)col[p], (unsigned)(NN - 1));
            u16x8 v = *(const u16x8*)(h + (size_t)c * 64 + f);
            #pragma unroll
            for (int j = 0; j < 8; j++) acc[i][j] += bf2f(v[j]);
        }
    }

    // reduce over slot groups (lane bits 3..5) for each node
    #pragma unroll
    for (int i = 0; i < 4; i++)
        #pragma unroll
        for (int off = 8; off < 64; off <<= 1)
            #pragma unroll
            for (int j = 0; j < 8; j++) acc[i][j] += __shfl_xor(acc[i][j], off);

    if (lane < 8) {
        #pragma unroll
        for (int i = 0; i < 4; i++) {
            int node = node0 + i;
            if (node < NN) {
                float inv = 1.f / fmaxf((float)dg[i], 1.f);
                u16x8 o;
                #pragma unroll
                for (int j = 0; j < 8; j++) o[j] = f2bf(acc[i][j] * inv);
                *(u16x8*)(out + (size_t)node * 64 + f) = o;
            }
        }
    }
}

// ---------------- MFMA GEMM kernels ----------------
// mfma_f32_16x16x32_bf16: C/D: col=lane&15, row=(lane>>4)*4+reg (m89/m91).

// layers 0,1: h_next = l2norm(relu(h@Ws + agg@Wn + b)) -> global
__global__ __launch_bounds__(256) void sage_mfma_kernel(
        const unsigned short* __restrict__ hin, unsigned short* __restrict__ hnb,
        const unsigned short* __restrict__ packS, const unsigned short* __restrict__ packN,
        const float* __restrict__ bias) {
    int wid = threadIdx.x >> 6, l = threadIdx.x & 63;
    int row_base = blockIdx.x * 64 + wid * 16;
    int arow = row_base + (l & 15);
    int koff = (l >> 4) * 8;
    bf16x8 z = {0, 0, 0, 0, 0, 0, 0, 0};
    bf16x8 aS0 = z, aS1 = z, aN0 = z, aN1 = z;
    if (arow < NN) {
        const unsigned short* hp = hin + (size_t)arow * 64 + koff;
        const unsigned short* np = hnb + (size_t)arow * 64 + koff;
        aS0 = *(const bf16x8*)(hp);
        aS1 = *(const bf16x8*)(hp + 32);
        aN0 = *(const bf16x8*)(np);
        aN1 = *(const bf16x8*)(np + 32);
    }
    int col0 = l & 15;
    int ro4 = (l >> 4) * 4;
    float ss0 = 0.f, ss1 = 0.f, ss2 = 0.f, ss3 = 0.f;
    f32x4 accs[4];
    #pragma unroll
    for (int nt = 0; nt < 4; nt++) {
        bf16x8 b0 = *(const bf16x8*)(packS + ((nt * 2 + 0) * 64 + l) * 8);
        bf16x8 b1 = *(const bf16x8*)(packS + ((nt * 2 + 1) * 64 + l) * 8);
        bf16x8 c0 = *(const bf16x8*)(packN + ((nt * 2 + 0) * 64 + l) * 8);
        bf16x8 c1 = *(const bf16x8*)(packN + ((nt * 2 + 1) * 64 + l) * 8);
        f32x4 acc = {0.f, 0.f, 0.f, 0.f};
        acc = __builtin_amdgcn_mfma_f32_16x16x32_bf16(aS0, b0, acc, 0, 0, 0);
        acc = __builtin_amdgcn_mfma_f32_16x16x32_bf16(aS1, b1, acc, 0, 0, 0);
        acc = __builtin_amdgcn_mfma_f32_16x16x32_bf16(aN0, c0, acc, 0, 0, 0);
        acc = __builtin_amdgcn_mfma_f32_16x16x32_bf16(aN1, c1, acc, 0, 0, 0);
        float bv = bias[nt * 16 + col0];
        #pragma unroll
        for (int j = 0; j < 4; j++) {
            float v = fmaxf(acc[j] + bv, 0.f);
            if (j == 0) ss0 = fmaf(v, v, ss0);
            if (j == 1) ss1 = fmaf(v, v, ss1);
            if (j == 2) ss2 = fmaf(v, v, ss2);
            if (j == 3) ss3 = fmaf(v, v, ss3);
            acc[j] = v;
        }
        accs[nt] = acc;
    }
    #pragma unroll
    for (int off = 1; off < 16; off <<= 1) {
        ss0 += __shfl_xor(ss0, off); ss1 += __shfl_xor(ss1, off);
        ss2 += __shfl_xor(ss2, off); ss3 += __shfl_xor(ss3, off);
    }
    float i0 = 1.f / fmaxf(sqrtf(ss0), 1e-12f);
    float i1 = 1.f / fmaxf(sqrtf(ss1), 1e-12f);
    float i2 = 1.f / fmaxf(sqrtf(ss2), 1e-12f);
    float i3 = 1.f / fmaxf(sqrtf(ss3), 1e-12f);
    #pragma unroll
    for (int nt = 0; nt < 4; nt++) {
        accs[nt][0] *= i0; accs[nt][1] *= i1; accs[nt][2] *= i2; accs[nt][3] *= i3;
    }
    #pragma unroll
    for (int j = 0; j < 4; j++) {
        int row = row_base + ro4 + j;
        if (row < NN) {
            #pragma unroll
            for (int nt = 0; nt < 4; nt++)
                hnb[(size_t)row * 64 + nt * 16 + col0] = f2bf(accs[nt][j]);
        }
    }
}

// fused layer-2 SAGE + head: h3 = h@Ws2 + agg@Wn2 + b2 (no act) -> LDS (bf16)
// -> fc -> BN -> ReLU -> softplus -> {z_loc, z_scale}. Never materializes h3.
__global__ __launch_bounds__(256) void sage_head_kernel(
        const unsigned short* __restrict__ hin, const unsigned short* __restrict__ hagg,
        const unsigned short* __restrict__ packS, const unsigned short* __restrict__ packN,
        const float* __restrict__ bias,
        const unsigned short* __restrict__ packFC, const float* __restrict__ fc_b,
        const float* __restrict__ bn_g, const float* __restrict__ bn_b,
        const float* __restrict__ bn_m, const float* __restrict__ bn_v,
        const unsigned short* __restrict__ pack21, const float* __restrict__ b21,
        const unsigned short* __restrict__ pack22, const float* __restrict__ b22,
        float* __restrict__ zloc, float* __restrict__ zscale) {
    __shared__ unsigned short tl[4][16][72];
    int wid = threadIdx.x >> 6, l = threadIdx.x & 63;
    int row_base = blockIdx.x * 64 + wid * 16;
    int arow = row_base + (l & 15);
    int koff = (l >> 4) * 8;
    int col0 = l & 15;
    int ro4 = (l >> 4) * 4;
    bf16x8 z = {0, 0, 0, 0, 0, 0, 0, 0};

    // stage 0: layer-2 SAGE (no activation) -> tl (bf16, row layout)
    {
        bf16x8 aS0 = z, aS1 = z, aN0 = z, aN1 = z;
        if (arow < NN) {
            const unsigned short* hp = hin + (size_t)arow * 64 + koff;
            const unsigned short* np = hagg + (size_t)arow * 64 + koff;
            aS0 = *(const bf16x8*)(hp);
            aS1 = *(const bf16x8*)(hp + 32);
            aN0 = *(const bf16x8*)(np);
            aN1 = *(const bf16x8*)(np + 32);
        }
        #pragma unroll
        for (int nt = 0; nt < 4; nt++) {
            bf16x8 b0 = *(const bf16x8*)(packS + ((nt * 2 + 0) * 64 + l) * 8);
            bf16x8 b1 = *(const bf16x8*)(packS + ((nt * 2 + 1) * 64 + l) * 8);
            bf16x8 c0 = *(const bf16x8*)(packN + ((nt * 2 + 0) * 64 + l) * 8);
            bf16x8 c1 = *(const bf16x8*)(packN + ((nt * 2 + 1) * 64 + l) * 8);
            f32x4 acc = {0.f, 0.f, 0.f, 0.f};
            acc = __builtin_amdgcn_mfma_f32_16x16x32_bf16(aS0, b0, acc, 0, 0, 0);
            acc = __builtin_amdgcn_mfma_f32_16x16x32_bf16(aS1, b1, acc, 0, 0, 0);
            acc = __builtin_amdgcn_mfma_f32_16x16x32_bf16(aN0, c0, acc, 0, 0, 0);
            acc = __builtin_amdgcn_mfma_f32_16x16x32_bf16(aN1, c1, acc, 0, 0, 0);
            int col = nt * 16 + col0;
            float bv = bias[col];
            #pragma unroll
            for (int j = 0; j < 4; j++)
                tl[wid][ro4 + j][col] = f2bf(acc[j] + bv);
        }
    }
    __syncthreads();
    bf16x8 a0 = *(const bf16x8*)(&tl[wid][l & 15][koff]);
    bf16x8 a1 = *(const bf16x8*)(&tl[wid][l & 15][32 + koff]);

    // stage 1: t = softplus(relu(BN(h3@fc_w + fc_b)))  -> tl
    #pragma unroll
    for (int nt = 0; nt < 4; nt++) {
        bf16x8 b0 = *(const bf16x8*)(packFC + ((nt * 2 + 0) * 64 + l) * 8);
        bf16x8 b1 = *(const bf16x8*)(packFC + ((nt * 2 + 1) * 64 + l) * 8);
        f32x4 acc = {0.f, 0.f, 0.f, 0.f};
        acc = __builtin_amdgcn_mfma_f32_16x16x32_bf16(a0, b0, acc, 0, 0, 0);
        acc = __builtin_amdgcn_mfma_f32_16x16x32_bf16(a1, b1, acc, 0, 0, 0);
        int col = nt * 16 + col0;
        float scale = bn_g[col] * rsqrtf(bn_v[col] + 1e-5f);
        float mm = bn_m[col], bb = bn_b[col], fb = fc_b[col];
        #pragma unroll
        for (int j = 0; j < 4; j++) {
            float u = (acc[j] + fb - mm) * scale + bb;
            u = fmaxf(u, 0.f);
            float t = u + __logf(1.f + __expf(-u));   // fast softplus, u>=0
            tl[wid][ro4 + j][col] = f2bf(t);
        }
    }
    __syncthreads();
    bf16x8 t0 = *(const bf16x8*)(&tl[wid][l & 15][koff]);
    bf16x8 t1 = *(const bf16x8*)(&tl[wid][l & 15][32 + koff]);

    // stage 2: z_loc = t@w21 + b21
    #pragma unroll
    for (int nt = 0; nt < 4; nt++) {
        bf16x8 b0 = *(const bf16x8*)(pack21 + ((nt * 2 + 0) * 64 + l) * 8);
        bf16x8 b1 = *(const bf16x8*)(pack21 + ((nt * 2 + 1) * 64 + l) * 8);
        f32x4 acc = {0.f, 0.f, 0.f, 0.f};
        acc = __builtin_amdgcn_mfma_f32_16x16x32_bf16(t0, b0, acc, 0, 0, 0);
        acc = __builtin_amdgcn_mfma_f32_16x16x32_bf16(t1, b1, acc, 0, 0, 0);
        int col = nt * 16 + col0;
        float bv = b21[col];
        #pragma unroll
        for (int j = 0; j < 4; j++) {
            int row = row_base + ro4 + j;
            if (row < NN) zloc[(size_t)row * 64 + col] = acc[j] + bv;
        }
    }

    // stage 3: z_scale = exp(t@w22 + b22)
    #pragma unroll
    for (int nt = 0; nt < 4; nt++) {
        bf16x8 b0 = *(const bf16x8*)(pack22 + ((nt * 2 + 0) * 64 + l) * 8);
        bf16x8 b1 = *(const bf16x8*)(pack22 + ((nt * 2 + 1) * 64 + l) * 8);
        f32x4 acc = {0.f, 0.f, 0.f, 0.f};
        acc = __builtin_amdgcn_mfma_f32_16x16x32_bf16(t0, b0, acc, 0, 0, 0);
        acc = __builtin_amdgcn_mfma_f32_16x16x32_bf16(t1, b1, acc, 0, 0, 0);
        int col = nt * 16 + col0;
        float bv = b22[col];
        #pragma unroll
        for (int j = 0; j < 4; j++) {
            int row = row_base + ro4 + j;
            if (row < NN) zscale[(size_t)row * 64 + col] = __expf(acc[j] + bv);
        }
    }
}

// ---------------- launch ----------------

extern "C" void kernel_launch(void* const* d_in, const int* in_sizes, int n_in,
                              void* d_out, int out_size, void* d_ws, size_t ws_size,
                              hipStream_t stream) {
    const float* x       = (const float*)d_in[0];
    const int*   esrc    = (const int*)d_in[1];
    const int*   edst    = (const int*)d_in[2];
    const float* W_self  = (const float*)d_in[3];
    const float* W_neigh = (const float*)d_in[4];
    const float* b_sage  = (const float*)d_in[5];
    const float* fc_w    = (const float*)d_in[6];
    const float* fc_b    = (const float*)d_in[7];
    const float* bn_g    = (const float*)d_in[8];
    const float* bn_b    = (const float*)d_in[9];
    const float* bn_m    = (const float*)d_in[10];
    const float* bn_v    = (const float*)d_in[11];
    const float* w21     = (const float*)d_in[12];
    const float* b21     = (const float*)d_in[13];
    const float* w22     = (const float*)d_in[14];
    const float* b22     = (const float*)d_in[15];

    float* zloc   = (float*)d_out;
    float* zscale = zloc + (size_t)NN * 64;

    unsigned short* hb0  = (unsigned short*)d_ws;
    unsigned short* hb1  = hb0 + (size_t)NN * 64;
    unsigned short* pack = hb1 + (size_t)NN * 64;
    int* pairs   = (int*)(pack + 9 * 4096);      // NB*CAP ints (4 MB)
    int* col     = pairs + NB * CAP;             // NB*CAP ints (4 MB)
    int* row_ptr = col + NB * CAP;
    int* row_cnt = row_ptr + NN;
    int* gcursor = row_cnt + NN;

    prep_kernel<<<(NN * 16 + 255) / 256, 256, 0, stream>>>(
        x, hb0, W_self, W_neigh, fc_w, w21, w22, pack, gcursor);
    bin_edges_kernel<<<(NE + EPB - 1) / EPB, 256, 0, stream>>>(
        esrc, edst, gcursor, pairs);
    csr_place_kernel<<<NB, 256, 0, stream>>>(pairs, gcursor, row_ptr, row_cnt, col);

    const int gemm_grid = (NN + 63) / 64;    // 64 rows/block
    const int agg_grid = (NN + 15) / 16;     // 4 waves/block x 4 nodes/wave

    // layers 0,1: aggregate + sage (materialized)
    unsigned short* hc = hb0;
    unsigned short* hn = hb1;
    for (int l = 0; l < 2; l++) {
        aggregate_kernel<<<agg_grid, 256, 0, stream>>>(hc, row_ptr, row_cnt, col, hn);
        sage_mfma_kernel<<<gemm_grid, 256, 0, stream>>>(
            hc, hn, pack + l * 4096, pack + (3 + l) * 4096, b_sage + l * 64);
        unsigned short* t = hc; hc = hn; hn = t;
    }
    // layer 2 aggregate, then fused sage2+head (h3 never touches global)
    aggregate_kernel<<<agg_grid, 256, 0, stream>>>(hc, row_ptr, row_cnt, col, hn);
    sage_head_kernel<<<gemm_grid, 256, 0, stream>>>(
        hc, hn, pack + 2 * 4096, pack + 5 * 4096, b_sage + 2 * 64,
        pack + 6 * 4096, fc_b, bn_g, bn_b, bn_m, bn_v,
        pack + 7 * 4096, b21, pack + 8 * 4096, b22, zloc, zscale);
}

// Round 16
// 194.690 us; speedup vs baseline: 1.0432x; 1.0432x over previous
//
#include <hip/hip_runtime.h>
#include <math.h>

#define NN 100000
#define NE 800000
#define NB 512          // dst buckets for CSR fill
#define CAP 2048        // padded per-bucket capacity (mean 1562, sigma 39.5)
#define EPB 4096        // edges per bin block

typedef short bf16x8 __attribute__((ext_vector_type(8)));
typedef float f32x4 __attribute__((ext_vector_type(4)));
typedef unsigned short u16x8 __attribute__((ext_vector_type(8)));
typedef unsigned short u16x4 __attribute__((ext_vector_type(4)));

__device__ __forceinline__ float bf2f(unsigned short u) {
    union { unsigned u32; float f; } c; c.u32 = ((unsigned)u) << 16; return c.f;
}
__device__ __forceinline__ unsigned short f2bf(float f) {
    union { float f; unsigned u; } c; c.f = f;
    unsigned u = c.u;
    unsigned r = (u + 0x7fffu + ((u >> 16) & 1u)) >> 16;   // RNE
    return (unsigned short)r;
}
__device__ __forceinline__ int bucket_of(int d) {
    return (int)(((long long)d * NB) / NN);
}
__device__ __forceinline__ int node_start_of(int b) {
    return (int)(((long long)b * NN) / NB);
}

// ---------------- fused prep: log1p + weight pack + gcursor zero -------------
__global__ __launch_bounds__(256) void prep_kernel(
        const float* __restrict__ x, unsigned short* __restrict__ h,
        const float* __restrict__ Wself, const float* __restrict__ Wneigh,
        const float* __restrict__ fcw, const float* __restrict__ w21,
        const float* __restrict__ w22, unsigned short* __restrict__ pack,
        int* __restrict__ gcursor) {
    int i = blockIdx.x * 256 + threadIdx.x;
    if (i < NN * 16) {
        float4 v = ((const float4*)x)[i];
        u16x4 o;
        o[0] = f2bf(__logf(v.x + 1.f)); o[1] = f2bf(__logf(v.y + 1.f));
        o[2] = f2bf(__logf(v.z + 1.f)); o[3] = f2bf(__logf(v.w + 1.f));
        ((u16x4*)h)[i] = o;
    }
    if (i < 9 * 4096) {
        int m = i / 4096, r = i % 4096;
        int e = r & 7, l = (r >> 3) & 63, kb = (r >> 9) & 1, nt = r >> 10;
        int k = kb * 32 + (l >> 4) * 8 + e;
        int n = nt * 16 + (l & 15);
        const float* src;
        if (m < 3) src = Wself + m * 4096;
        else if (m < 6) src = Wneigh + (m - 3) * 4096;
        else if (m == 6) src = fcw;
        else if (m == 7) src = w21;
        else src = w22;
        pack[i] = f2bf(src[k * 64 + n]);
    }
    if (i < NB) gcursor[i] = 0;
}

// ---------------- CSR build: padded buckets ----------------

__global__ __launch_bounds__(256) void bin_edges_kernel(
        const int* __restrict__ src, const int* __restrict__ dst,
        int* __restrict__ gcursor, int* __restrict__ pairs) {
    __shared__ int hist[NB];
    __shared__ int base[NB];
    int e0 = blockIdx.x * EPB;
    int e1 = min(e0 + EPB, NE);
    for (int i = threadIdx.x; i < NB; i += 256) hist[i] = 0;
    __syncthreads();
    for (int e = e0 + threadIdx.x; e < e1; e += 256)
        atomicAdd(&hist[bucket_of(dst[e])], 1);
    __syncthreads();
    for (int i = threadIdx.x; i < NB; i += 256) {
        int c = hist[i];
        base[i] = c ? atomicAdd(&gcursor[i], c) : 0;
        hist[i] = 0;
    }
    __syncthreads();
    for (int e = e0 + threadIdx.x; e < e1; e += 256) {
        int d = dst[e];
        int b = bucket_of(d);
        int li = d - node_start_of(b);          // < 196, fits 8 bits
        int r = atomicAdd(&hist[b], 1);
        unsigned loc = (unsigned)(base[b] + r);
        if (loc < CAP) pairs[b * CAP + loc] = (src[e] << 8) | li;  // overflow -> drop
    }
}

__global__ __launch_bounds__(256) void csr_place_kernel(
        const int* __restrict__ pairs, const int* __restrict__ gcursor,
        int* __restrict__ row_ptr, int* __restrict__ row_cnt,
        int* __restrict__ col) {
    int b = blockIdx.x;
    int ns = node_start_of(b);
    int cnt = node_start_of(b + 1) - ns;     // <= 196
    int eb = b * CAP;
    int ecount = min(gcursor[b], CAP);
    __shared__ int cur[200];
    __shared__ int off[200];
    for (int i = threadIdx.x; i < cnt; i += 256) cur[i] = 0;
    __syncthreads();
    for (int p = threadIdx.x; p < ecount; p += 256) {
        int li = pairs[eb + p] & 255;
        if (li < cnt) atomicAdd(&cur[li], 1);
    }
    __syncthreads();
    if (threadIdx.x == 0) {
        int run = 0;
        for (int i = 0; i < cnt; i++) { off[i] = run; run += cur[i]; }
    }
    __syncthreads();
    for (int i = threadIdx.x; i < cnt; i += 256) {
        int c = cur[i];
        row_ptr[ns + i] = eb + off[i];
        row_cnt[ns + i] = c;
        cur[i] = 0;
    }
    __syncthreads();
    for (int p = threadIdx.x; p < ecount; p += 256) {
        int pr = pairs[eb + p];
        int li = pr & 255;
        if (li < cnt) {
            int pos = atomicAdd(&cur[li], 1);
            unsigned q = (unsigned)(off[li] + pos);
            if (q < CAP) col[eb + q] = pr >> 8;   // guard: skip, not fault
        }
    }
}

// ---------------- aggregate: one wave per node ----------------
__global__ __launch_bounds__(256) void aggregate_kernel(
        const unsigned short* __restrict__ h, const int* __restrict__ row_ptr,
        const int* __restrict__ row_cnt, const int* __restrict__ col,
        unsigned short* __restrict__ out) {
    int gt = blockIdx.x * 256 + threadIdx.x;
    int node = gt >> 6;
    if (node >= NN) return;
    int lane = threadIdx.x & 63;
    int slot = lane >> 3;
    int f = (lane & 7) * 8;
    int beg = row_ptr[node];
    int dg = row_cnt[node];
    int end = beg + dg;
    float a0 = 0.f, a1 = 0.f, a2 = 0.f, a3 = 0.f, a4 = 0.f, a5 = 0.f, a6 = 0.f, a7 = 0.f;
    for (int p = beg + slot; p < end; p += 16) {
        int p1 = p + 8;
        unsigned s0 = min((unsigned)col[p], (unsigned)(NN - 1));      // clamp
        u16x8 v0 = *(const u16x8*)(h + (size_t)s0 * 64 + f);
        if (p1 < end) {
            unsigned s1 = min((unsigned)col[p1], (unsigned)(NN - 1)); // clamp
            u16x8 v1 = *(const u16x8*)(h + (size_t)s1 * 64 + f);
            a0 += bf2f(v1[0]); a1 += bf2f(v1[1]); a2 += bf2f(v1[2]); a3 += bf2f(v1[3]);
            a4 += bf2f(v1[4]); a5 += bf2f(v1[5]); a6 += bf2f(v1[6]); a7 += bf2f(v1[7]);
        }
        a0 += bf2f(v0[0]); a1 += bf2f(v0[1]); a2 += bf2f(v0[2]); a3 += bf2f(v0[3]);
        a4 += bf2f(v0[4]); a5 += bf2f(v0[5]); a6 += bf2f(v0[6]); a7 += bf2f(v0[7]);
    }
    #pragma unroll
    for (int off = 8; off < 64; off <<= 1) {
        a0 += __shfl_xor(a0, off); a1 += __shfl_xor(a1, off);
        a2 += __shfl_xor(a2, off); a3 += __shfl_xor(a3, off);
        a4 += __shfl_xor(a4, off); a5 += __shfl_xor(a5, off);
        a6 += __shfl_xor(a6, off); a7 += __shfl_xor(a7, off);
    }
    if (lane < 8) {
        float inv = 1.f / fmaxf((float)dg, 1.f);
        u16x8 o;
        o[0] = f2bf(a0 * inv); o[1] = f2bf(a1 * inv); o[2] = f2bf(a2 * inv); o[3] = f2bf(a3 * inv);
        o[4] = f2bf(a4 * inv); o[5] = f2bf(a5 * inv); o[6] = f2bf(a6 * inv); o[7] = f2bf(a7 * inv);
        *(u16x8*)(out + (size_t)node * 64 + f) = o;
    }
}

// ---------------- MFMA GEMM kernels ----------------
// mfma_f32_16x16x32_bf16: C/D: col=lane&15, row=(lane>>4)*4+reg (m89/m91).

// layers 0,1: h_next = l2norm(relu(h@Ws + agg@Wn + b)) -> global
__global__ __launch_bounds__(256) void sage_mfma_kernel(
        const unsigned short* __restrict__ hin, unsigned short* __restrict__ hnb,
        const unsigned short* __restrict__ packS, const unsigned short* __restrict__ packN,
        const float* __restrict__ bias) {
    int wid = threadIdx.x >> 6, l = threadIdx.x & 63;
    int row_base = blockIdx.x * 64 + wid * 16;
    int arow = row_base + (l & 15);
    int koff = (l >> 4) * 8;
    bf16x8 z = {0, 0, 0, 0, 0, 0, 0, 0};
    bf16x8 aS0 = z, aS1 = z, aN0 = z, aN1 = z;
    if (arow < NN) {
        const unsigned short* hp = hin + (size_t)arow * 64 + koff;
        const unsigned short* np = hnb + (size_t)arow * 64 + koff;
        aS0 = *(const bf16x8*)(hp);
        aS1 = *(const bf16x8*)(hp + 32);
        aN0 = *(const bf16x8*)(np);
        aN1 = *(const bf16x8*)(np + 32);
    }
    int col0 = l & 15;
    int ro4 = (l >> 4) * 4;
    float ss0 = 0.f, ss1 = 0.f, ss2 = 0.f, ss3 = 0.f;
    f32x4 accs[4];
    #pragma unroll
    for (int nt = 0; nt < 4; nt++) {
        bf16x8 b0 = *(const bf16x8*)(packS + ((nt * 2 + 0) * 64 + l) * 8);
        bf16x8 b1 = *(const bf16x8*)(packS + ((nt * 2 + 1) * 64 + l) * 8);
        bf16x8 c0 = *(const bf16x8*)(packN + ((nt * 2 + 0) * 64 + l) * 8);
        bf16x8 c1 = *(const bf16x8*)(packN + ((nt * 2 + 1) * 64 + l) * 8);
        f32x4 acc = {0.f, 0.f, 0.f, 0.f};
        acc = __builtin_amdgcn_mfma_f32_16x16x32_bf16(aS0, b0, acc, 0, 0, 0);
        acc = __builtin_amdgcn_mfma_f32_16x16x32_bf16(aS1, b1, acc, 0, 0, 0);
        acc = __builtin_amdgcn_mfma_f32_16x16x32_bf16(aN0, c0, acc, 0, 0, 0);
        acc = __builtin_amdgcn_mfma_f32_16x16x32_bf16(aN1, c1, acc, 0, 0, 0);
        float bv = bias[nt * 16 + col0];
        #pragma unroll
        for (int j = 0; j < 4; j++) {
            float v = fmaxf(acc[j] + bv, 0.f);
            if (j == 0) ss0 = fmaf(v, v, ss0);
            if (j == 1) ss1 = fmaf(v, v, ss1);
            if (j == 2) ss2 = fmaf(v, v, ss2);
            if (j == 3) ss3 = fmaf(v, v, ss3);
            acc[j] = v;
        }
        accs[nt] = acc;
    }
    #pragma unroll
    for (int off = 1; off < 16; off <<= 1) {
        ss0 += __shfl_xor(ss0, off); ss1 += __shfl_xor(ss1, off);
        ss2 += __shfl_xor(ss2, off); ss3 += __shfl_xor(ss3, off);
    }
    float i0 = 1.f / fmaxf(sqrtf(ss0), 1e-12f);
    float i1 = 1.f / fmaxf(sqrtf(ss1), 1e-12f);
    float i2 = 1.f / fmaxf(sqrtf(ss2), 1e-12f);
    float i3 = 1.f / fmaxf(sqrtf(ss3), 1e-12f);
    #pragma unroll
    for (int nt = 0; nt < 4; nt++) {
        accs[nt][0] *= i0; accs[nt][1] *= i1; accs[nt][2] *= i2; accs[nt][3] *= i3;
    }
    #pragma unroll
    for (int j = 0; j < 4; j++) {
        int row = row_base + ro4 + j;
        if (row < NN) {
            #pragma unroll
            for (int nt = 0; nt < 4; nt++)
                hnb[(size_t)row * 64 + nt * 16 + col0] = f2bf(accs[nt][j]);
        }
    }
}

// fused layer-2 SAGE + head: h3 = h@Ws2 + agg@Wn2 + b2 (no act) -> LDS (bf16)
// -> fc -> BN -> ReLU -> softplus -> {z_loc, z_scale}. Never materializes h3.
__global__ __launch_bounds__(256) void sage_head_kernel(
        const unsigned short* __restrict__ hin, const unsigned short* __restrict__ hagg,
        const unsigned short* __restrict__ packS, const unsigned short* __restrict__ packN,
        const float* __restrict__ bias,
        const unsigned short* __restrict__ packFC, const float* __restrict__ fc_b,
        const float* __restrict__ bn_g, const float* __restrict__ bn_b,
        const float* __restrict__ bn_m, const float* __restrict__ bn_v,
        const unsigned short* __restrict__ pack21, const float* __restrict__ b21,
        const unsigned short* __restrict__ pack22, const float* __restrict__ b22,
        float* __restrict__ zloc, float* __restrict__ zscale) {
    __shared__ unsigned short tl[4][16][72];
    int wid = threadIdx.x >> 6, l = threadIdx.x & 63;
    int row_base = blockIdx.x * 64 + wid * 16;
    int arow = row_base + (l & 15);
    int koff = (l >> 4) * 8;
    int col0 = l & 15;
    int ro4 = (l >> 4) * 4;
    bf16x8 z = {0, 0, 0, 0, 0, 0, 0, 0};

    // stage 0: layer-2 SAGE (no activation) -> tl (bf16, row layout)
    {
        bf16x8 aS0 = z, aS1 = z, aN0 = z, aN1 = z;
        if (arow < NN) {
            const unsigned short* hp = hin + (size_t)arow * 64 + koff;
            const unsigned short* np = hagg + (size_t)arow * 64 + koff;
            aS0 = *(const bf16x8*)(hp);
            aS1 = *(const bf16x8*)(hp + 32);
            aN0 = *(const bf16x8*)(np);
            aN1 = *(const bf16x8*)(np + 32);
        }
        #pragma unroll
        for (int nt = 0; nt < 4; nt++) {
            bf16x8 b0 = *(const bf16x8*)(packS + ((nt * 2 + 0) * 64 + l) * 8);
            bf16x8 b1 = *(const bf16x8*)(packS + ((nt * 2 + 1) * 64 + l) * 8);
            bf16x8 c0 = *(const bf16x8*)(packN + ((nt * 2 + 0) * 64 + l) * 8);
            bf16x8 c1 = *(const bf16x8*)(packN + ((nt * 2 + 1) * 64 + l) * 8);
            f32x4 acc = {0.f, 0.f, 0.f, 0.f};
            acc = __builtin_amdgcn_mfma_f32_16x16x32_bf16(aS0, b0, acc, 0, 0, 0);
            acc = __builtin_amdgcn_mfma_f32_16x16x32_bf16(aS1, b1, acc, 0, 0, 0);
            acc = __builtin_amdgcn_mfma_f32_16x16x32_bf16(aN0, c0, acc, 0, 0, 0);
            acc = __builtin_amdgcn_mfma_f32_16x16x32_bf16(aN1, c1, acc, 0, 0, 0);
            int col = nt * 16 + col0;
            float bv = bias[col];
            #pragma unroll
            for (int j = 0; j < 4; j++)
                tl[wid][ro4 + j][col] = f2bf(acc[j] + bv);
        }
    }
    __syncthreads();
    bf16x8 a0 = *(const bf16x8*)(&tl[wid][l & 15][koff]);
    bf16x8 a1 = *(const bf16x8*)(&tl[wid][l & 15][32 + koff]);

    // stage 1: t = softplus(relu(BN(h3@fc_w + fc_b)))  -> tl
    #pragma unroll
    for (int nt = 0; nt < 4; nt++) {
        bf16x8 b0 = *(const bf16x8*)(packFC + ((nt * 2 + 0) * 64 + l) * 8);
        bf16x8 b1 = *(const bf16x8*)(packFC + ((nt * 2 + 1) * 64 + l) * 8);
        f32x4 acc = {0.f, 0.f, 0.f, 0.f};
        acc = __builtin_amdgcn_mfma_f32_16x16x32_bf16(a0, b0, acc, 0, 0, 0);
        acc = __builtin_amdgcn_mfma_f32_16x16x32_bf16(a1, b1, acc, 0, 0, 0);
        int col = nt * 16 + col0;
        float scale = bn_g[col] * rsqrtf(bn_v[col] + 1e-5f);
        float mm = bn_m[col], bb = bn_b[col], fb = fc_b[col];
        #pragma unroll
        for (int j = 0; j < 4; j++) {
            float u = (acc[j] + fb - mm) * scale + bb;
            u = fmaxf(u, 0.f);
            float t = u + __logf(1.f + __expf(-u));   // fast softplus, u>=0
            tl[wid][ro4 + j][col] = f2bf(t);
        }
    }
    __syncthreads();
    bf16x8 t0 = *(const bf16x8*)(&tl[wid][l & 15][koff]);
    bf16x8 t1 = *(const bf16x8*)(&tl[wid][l & 15][32 + koff]);

    // stage 2: z_loc = t@w21 + b21
    #pragma unroll
    for (int nt = 0; nt < 4; nt++) {
        bf16x8 b0 = *(const bf16x8*)(pack21 + ((nt * 2 + 0) * 64 + l) * 8);
        bf16x8 b1 = *(const bf16x8*)(pack21 + ((nt * 2 + 1) * 64 + l) * 8);
        f32x4 acc = {0.f, 0.f, 0.f, 0.f};
        acc = __builtin_amdgcn_mfma_f32_16x16x32_bf16(t0, b0, acc, 0, 0, 0);
        acc = __builtin_amdgcn_mfma_f32_16x16x32_bf16(t1, b1, acc, 0, 0, 0);
        int col = nt * 16 + col0;
        float bv = b21[col];
        #pragma unroll
        for (int j = 0; j < 4; j++) {
            int row = row_base + ro4 + j;
            if (row < NN) zloc[(size_t)row * 64 + col] = acc[j] + bv;
        }
    }

    // stage 3: z_scale = exp(t@w22 + b22)
    #pragma unroll
    for (int nt = 0; nt < 4; nt++) {
        bf16x8 b0 = *(const bf16x8*)(pack22 + ((nt * 2 + 0) * 64 + l) * 8);
        bf16x8 b1 = *(const bf16x8*)(pack22 + ((nt * 2 + 1) * 64 + l) * 8);
        f32x4 acc = {0.f, 0.f, 0.f, 0.f};
        acc = __builtin_amdgcn_mfma_f32_16x16x32_bf16(t0, b0, acc, 0, 0, 0);
        acc = __builtin_amdgcn_mfma_f32_16x16x32_bf16(t1, b1, acc, 0, 0, 0);
        int col = nt * 16 + col0;
        float bv = b22[col];
        #pragma unroll
        for (int j = 0; j < 4; j++) {
            int row = row_base + ro4 + j;
            if (row < NN) zscale[(size_t)row * 64 + col] = __expf(acc[j] + bv);
        }
    }
}

// ---------------- launch ----------------

extern "C" void kernel_launch(void* const* d_in, const int* in_sizes, int n_in,
                              void* d_out, int out_size, void* d_ws, size_t ws_size,
                              hipStream_t stream) {
    const float* x       = (const float*)d_in[0];
    const int*   esrc    = (const int*)d_in[1];
    const int*   edst    = (const int*)d_in[2];
    const float* W_self  = (const float*)d_in[3];
    const float* W_neigh = (const float*)d_in[4];
    const float* b_sage  = (const float*)d_in[5];
    const float* fc_w    = (const float*)d_in[6];
    const float* fc_b    = (const float*)d_in[7];
    const float* bn_g    = (const float*)d_in[8];
    const float* bn_b    = (const float*)d_in[9];
    const float* bn_m    = (const float*)d_in[10];
    const float* bn_v    = (const float*)d_in[11];
    const float* w21     = (const float*)d_in[12];
    const float* b21     = (const float*)d_in[13];
    const float* w22     = (const float*)d_in[14];
    const float* b22     = (const float*)d_in[15];

    float* zloc   = (float*)d_out;
    float* zscale = zloc + (size_t)NN * 64;

    unsigned short* hb0  = (unsigned short*)d_ws;
    unsigned short* hb1  = hb0 + (size_t)NN * 64;
    unsigned short* pack = hb1 + (size_t)NN * 64;
    int* pairs   = (int*)(pack + 9 * 4096);      // NB*CAP ints (4 MB)
    int* col     = pairs + NB * CAP;             // NB*CAP ints (4 MB)
    int* row_ptr = col + NB * CAP;
    int* row_cnt = row_ptr + NN;
    int* gcursor = row_cnt + NN;

    prep_kernel<<<(NN * 16 + 255) / 256, 256, 0, stream>>>(
        x, hb0, W_self, W_neigh, fc_w, w21, w22, pack, gcursor);
    bin_edges_kernel<<<(NE + EPB - 1) / EPB, 256, 0, stream>>>(
        esrc, edst, gcursor, pairs);
    csr_place_kernel<<<NB, 256, 0, stream>>>(pairs, gcursor, row_ptr, row_cnt, col);

    const int gemm_grid = (NN + 63) / 64;    // 64 rows/block
    const int agg_grid = (NN * 64 + 255) / 256;

    // layers 0,1: aggregate + sage (materialized)
    unsigned short* hc = hb0;
    unsigned short* hn = hb1;
    for (int l = 0; l < 2; l++) {
        aggregate_kernel<<<agg_grid, 256, 0, stream>>>(hc, row_ptr, row_cnt, col, hn);
        sage_mfma_kernel<<<gemm_grid, 256, 0, stream>>>(
            hc, hn, pack + l * 4096, pack + (3 + l) * 4096, b_sage + l * 64);
        unsigned short* t = hc; hc = hn; hn = t;
    }
    // layer 2 aggregate, then fused sage2+head (h3 never touches global)
    aggregate_kernel<<<agg_grid, 256, 0, stream>>>(hc, row_ptr, row_cnt, col, hn);
    sage_head_kernel<<<gemm_grid, 256, 0, stream>>>(
        hc, hn, pack + 2 * 4096, pack + 5 * 4096, b_sage + 2 * 64,
        pack + 6 * 4096, fc_b, bn_g, bn_b, bn_m, bn_v,
        pack + 7 * 4096, b21, pack + 8 * 4096, b22, zloc, zscale);
}